// Round 11
// baseline (142.255 us; speedup 1.0000x reference)
//
#include <hip/hip_runtime.h>

// Problem constants (from reference): B=4, N=100000, C=500, H=W=512.
#define B_DIM 4
#define N_DIM 100000
#define C_DIM 500
#define TOTAL_ROWS (B_DIM * N_DIM)   // 400000
#define NQUAD (TOTAL_ROWS / 4)       // 100000 (4 rows per wave-iteration)
#define IMG_W 512.0f
#define IMG_H 512.0f

typedef float floatx4 __attribute__((ext_vector_type(4)));

// R11 = R10 with the final iteration PEELED instead of clamp-prefetched:
// R4-R10 ended every wave with a dummy 8KB nt prefetch of quad 0 (4096 waves
// x 8KB = up to 32MB junk HBM reads, nt defeats L2 absorption). Peeling keeps
// the in-loop prefetch unconditional (exact counted-vmcnt scoreboard, the R4
// lesson) while eliminating the junk traffic.
// Everything else proven & kept: nt cls loads, XCD-contiguous remap (1024 ->
// 128 blocks/XCD exact), depth-1 prefetch, 4 rows/iter, grid 1024.

__device__ __forceinline__ void scan4(floatx4 q, int i0, float& best, int& bidx) {
    if (q.x > best) { best = q.x; bidx = i0;     }
    if (q.y > best) { best = q.y; bidx = i0 + 1; }
    if (q.z > best) { best = q.z; bidx = i0 + 2; }
    if (q.w > best) { best = q.w; bidx = i0 + 3; }
}

struct Stage {
    floatx4 q0[4], q1[4];   // cls: rows 0..3 x (chunk0, chunk1)
    floatx4 a, r;           // anchors / regressions for row base+lidx
};

__device__ __forceinline__ Stage load_stage(
    const float* __restrict__ cls, const float* __restrict__ anchors,
    const float* __restrict__ reg, int quad, int lane, int v1, int lidx)
{
    Stage s;
    const int base = quad * 4;
    #pragma unroll
    for (int t = 0; t < 4; ++t) {
        const floatx4* p = (const floatx4*)(cls + (size_t)(base + t) * C_DIM);
        s.q0[t] = __builtin_nontemporal_load(p + lane);
        s.q1[t] = __builtin_nontemporal_load(p + v1);
    }
    const int rw = base + lidx;
    s.a = *(const floatx4*)(anchors + (size_t)(rw % N_DIM) * 4);
    s.r = *(const floatx4*)(reg + (size_t)rw * 4);
    return s;
}

__global__ __launch_bounds__(256) void InferenceTransform_66202625900988_kernel(
    const float* __restrict__ cls,       // [B,N,C]
    const float* __restrict__ reg,       // [B,N,4]
    const float* __restrict__ anchors,   // [1,N,4]
    const float* __restrict__ thresh_p,  // [1]
    const float* __restrict__ rfac,      // [4]
    float* __restrict__ out)             // boxes[B*N*4] | cls[B*N] | scores[B*N] | mask[B*N]
{
    const int lane          = threadIdx.x & 63;
    const int waveInBlock   = threadIdx.x >> 6;
    const int wavesPerBlock = blockDim.x >> 6;
    const int nWaves        = gridDim.x * wavesPerBlock;   // 4096

    // XCD-contiguous remap (grid=1024 -> 128 blocks/XCD exactly; bijective).
    const int xcd    = blockIdx.x & 7;
    const int slot   = blockIdx.x >> 3;
    const int waveId = (xcd * (gridDim.x >> 3) + slot) * wavesPerBlock + waveInBlock;

    const int v1   = (lane + 64 < C_DIM / 4) ? (lane + 64) : (C_DIM / 4 - 1);
    const int lidx = (lane < 4) ? lane : 3;   // lanes >=4 replicate lane 3

    const float thresh = thresh_p[0];
    const float rf0 = rfac[0], rf1 = rfac[1], rf2 = rfac[2], rf3 = rfac[3];

    float*       outBoxes = out;
    float*       outCls   = out + (size_t)TOTAL_ROWS * 4;
    float*       outScore = outCls + (size_t)TOTAL_ROWS;
    float*       outMask  = outScore + (size_t)TOTAL_ROWS;

    // Process one quad held in `st` (rows base..base+3).
    auto process = [&](int base, const Stage& st) {
        float loc[4] = {-1.0f, -1.0f, -1.0f, -1.0f};
        int   bx[4]  = {0, 0, 0, 0};
        #pragma unroll
        for (int t = 0; t < 4; ++t) {
            scan4(st.q0[t], 4 * lane, loc[t], bx[t]);
            scan4(st.q1[t], 4 * v1,   loc[t], bx[t]);   // dup lanes carry true idx
        }

        // Four interleaved value-only butterflies (ILP on the DS pipe).
        float w[4] = {loc[0], loc[1], loc[2], loc[3]};
        #pragma unroll
        for (int off = 32; off > 0; off >>= 1) {
            #pragma unroll
            for (int t = 0; t < 4; ++t)
                w[t] = fmaxf(w[t], __shfl_xor(w[t], off, 64));
        }

        // Argmax per row: prefer chunk-0 (idx<256); idx monotone in lane
        // within a chunk -> lowest set lane = first occurrence.
        int ridx[4];
        #pragma unroll
        for (int t = 0; t < 4; ++t) {
            unsigned long long ca = __ballot(loc[t] == w[t] && bx[t] < 256);
            unsigned long long c  = ca ? ca : __ballot(loc[t] == w[t]);
            ridx[t] = __shfl(bx[t], (int)__builtin_ctzll(c), 64);
        }

        // Epilogue on ALL lanes: lanes 0..3 -> rows base..base+3; lanes >=4
        // replicate lane 3 (dup-address stores coalesce).
        const int   row  = base + lidx;
        const float best = (lidx == 0) ? w[0] : (lidx == 1) ? w[1]
                         : (lidx == 2) ? w[2] : w[3];
        const int   bidx = (lidx == 0) ? ridx[0] : (lidx == 1) ? ridx[1]
                         : (lidx == 2) ? ridx[2] : ridx[3];

        float width  = st.a.z - st.a.x;
        float height = st.a.w - st.a.y;
        float ctrx   = st.a.x + 0.5f * width;
        float ctry   = st.a.y + 0.5f * height;

        float px = ctrx + (st.r.x * rf0) * width;
        float py = ctry + (st.r.y * rf1) * height;
        float pw = __expf(st.r.z * rf2) * width;
        float ph = __expf(st.r.w * rf3) * height;

        float x1 = fminf(fmaxf(px - 0.5f * pw, 0.0f), IMG_W);
        float y1 = fminf(fmaxf(py - 0.5f * ph, 0.0f), IMG_H);
        float x2 = fminf(fmaxf(px + 0.5f * pw, 0.0f), IMG_W);
        float y2 = fminf(fmaxf(py + 0.5f * ph, 0.0f), IMG_H);

        const float m = (best > thresh) ? 1.0f : 0.0f;

        floatx4 box;
        box.x = x1 * m; box.y = y1 * m; box.z = x2 * m; box.w = y2 * m;
        *(floatx4*)(outBoxes + (size_t)row * 4) = box;  // 4 rows = 64B line
        outCls[row]   = m != 0.0f ? (float)bidx : 0.0f;
        outScore[row] = best * m;
        outMask[row]  = m;
    };

    int quad = waveId;   // 4096 waves <= 100000 quads: all waves have work
    Stage cur = load_stage(cls, anchors, reg, quad, lane, v1, lidx);

    int nq = quad + nWaves;
    while (nq < NQUAD) {
        // Unconditional in-loop prefetch: exact scoreboard, counted vmcnt.
        Stage nxt = load_stage(cls, anchors, reg, nq, lane, v1, lidx);
        process(quad * 4, cur);
        quad = nq;
        cur  = nxt;
        nq   = quad + nWaves;
    }
    // Peeled final iteration: no prefetch -> no junk HBM traffic.
    process(quad * 4, cur);
}

extern "C" void kernel_launch(void* const* d_in, const int* in_sizes, int n_in,
                              void* d_out, int out_size, void* d_ws, size_t ws_size,
                              hipStream_t stream) {
    // Input order per setup_inputs(): imgs, classifications, regressions,
    // anchors, cls_thresh, regress_factor.
    const float* cls     = (const float*)d_in[1];
    const float* reg     = (const float*)d_in[2];
    const float* anchors = (const float*)d_in[3];
    const float* thresh  = (const float*)d_in[4];
    const float* rfac    = (const float*)d_in[5];
    float* out = (float*)d_out;

    const int block = 256;   // 4 waves/block
    const int grid  = 1024;  // 16 waves/CU resident; 128 blocks/XCD exact

    InferenceTransform_66202625900988_kernel<<<grid, block, 0, stream>>>(
        cls, reg, anchors, thresh, rfac, out);
}